// Round 1
// 357.178 us; speedup vs baseline: 1.0429x; 1.0429x over previous
//
#include <hip/hip_runtime.h>
#include <hip/hip_bf16.h>

typedef unsigned short ushort_t;
typedef __attribute__((ext_vector_type(8))) short short8;
typedef __attribute__((ext_vector_type(4))) float f32x4;

#define NCOMP    8
#define CIN      512
#define COUT     256
#define H        64
#define HP       66      // padded spatial dim (halo 1 each side)
#define OHW      128
#define NB       8

// Cayley-Dickson |comp| table for n=8 (verified in round 1); sign(i,j)=+1 iff i>=j.
__device__ const int d_idx8[8][8] = {
    {0,1,2,1,4,3,2,3},
    {1,0,3,2,5,4,1,2},
    {2,1,0,1,6,5,4,3},
    {3,2,1,0,7,6,5,4},
    {4,3,2,3,0,1,2,1},
    {5,4,1,2,1,0,3,2},
    {6,5,4,3,2,1,0,1},
    {7,6,5,4,3,2,1,0}};

// Tap tables (verified by round-1 kernel's parity math):
// output parity p, tap index a: kernel index kh and input offset dh (ih = ohh + dh).
__device__ const int kh_tab[2][2] = {{1,3},{0,2}};
__device__ const int dh_tab[2][2] = {{0,-1},{1,0}};

// ---------------- halo zeroing (replaces full-buffer memset) ----------------
// Interior cells are fully overwritten by prep_x every launch; only the halo
// (ih in {0,65} any iw, plus iw in {0,65} for ih 1..64) must be zeroed.
__global__ void zero_halo(ushort_t* __restrict__ xpadT) {
    const int t = blockIdx.x * 256 + threadIdx.x;
    const int nA = 8 * 2 * 66 * 64;   // top+bottom full rows, 64 x 16B per cell
    short8 z = {0, 0, 0, 0, 0, 0, 0, 0};
    if (t < nA) {
        int v  = t & 63;
        int r  = t >> 6;              // (b*2 + e)*66 + iw
        int iw = r % 66;
        int q  = r / 66;              // b*2 + e
        int ih = (q & 1) * 65;
        int b  = q >> 1;
        *(short8*)(xpadT + (((size_t)b * HP + ih) * HP + iw) * CIN + v * 8) = z;
    } else {                          // left+right cols, ih 1..64
        int u  = t - nA;              // < 8*64*2*64 by grid sizing
        int v  = u & 63;
        int r  = u >> 6;              // (b*64 + ih-1)*2 + e
        int e  = r & 1;
        int q  = r >> 1;
        int ih = (q & 63) + 1;
        int b  = q >> 6;
        int iw = e * 65;
        *(short8*)(xpadT + (((size_t)b * HP + ih) * HP + iw) * CIN + v * 8) = z;
    }
}

// ---------------- prep: x -> padded, transposed, bf16 ----------------
// xpadT[b][ih+1][iw+1][ic]  (bf16, halo rows/cols pre-zeroed by zero_halo)
__global__ void prep_x(const float* __restrict__ x, ushort_t* __restrict__ xpadT) {
    __shared__ ushort_t tile[32][33];
    const int ih  = blockIdx.x;          // 0..63
    const int iw0 = (blockIdx.y & 1) * 32;
    const int ic0 = (blockIdx.y >> 1) * 32;
    const int b   = blockIdx.z;
    const int t   = threadIdx.x;         // 0..255

    for (int e = t; e < 1024; e += 256) {
        int icl = e >> 5, iwl = e & 31;
        float v = x[(((size_t)b * CIN + ic0 + icl) * H + ih) * H + iw0 + iwl];
        __hip_bfloat16 h = __float2bfloat16(v);
        tile[icl][iwl] = *(ushort_t*)&h;
    }
    __syncthreads();
    const int iwl = t >> 3, g = t & 7;   // 32 iw x 8 groups of 4 ic
    ushort4 v;
    v.x = tile[g * 4 + 0][iwl];
    v.y = tile[g * 4 + 1][iwl];
    v.z = tile[g * 4 + 2][iwl];
    v.w = tile[g * 4 + 3][iwl];
    ushort_t* dst = xpadT + (((size_t)b * HP + ih + 1) * HP + iw0 + iwl + 1) * CIN + ic0 + g * 4;
    *(ushort4*)dst = v;
}

// ---------------- prep: fused bf16 weights + bias ----------------
// Abf layout [cls][ks(64)][oc(256)][kin(32)] so each K-step's A-tile is a
// contiguous 8KB block (global_load_lds-friendly).
__global__ void prep_w(const float* __restrict__ W, const float* __restrict__ bias,
                       ushort_t* __restrict__ Abf, float* __restrict__ bbig) {
    const int t = blockIdx.x * blockDim.x + threadIdx.x;
    if (t < 4 * 64 * 256 * 32) {
        int kin = t & 31;
        int oc  = (t >> 5) & 255;
        int ks  = (t >> 13) & 63;
        int cls = t >> 19;
        int k  = ks * 32 + kin;
        int a  = k >> 10, c = (k >> 9) & 1, ic = k & 511;
        int ph = cls >> 1, pw = cls & 1;
        int kh = kh_tab[ph][a], kw = kh_tab[pw][c];
        int i = oc >> 5, co = oc & 31;
        int j = ic >> 6, ci = ic & 63;
        float s = (i >= j) ? 1.0f : -1.0f;
        float v = s * W[(((size_t)(d_idx8[i][j] * 64 + ci) * 32 + co) * 4 + kh) * 4 + kw];
        __hip_bfloat16 h = __float2bfloat16(v);
        Abf[t] = *(ushort_t*)&h;
    }
    if (t < COUT) {
        int i = t >> 5, co = t & 31;
        float acc = 0.0f;
        for (int j = 0; j < NCOMP; ++j)
            acc += ((i >= j) ? 1.0f : -1.0f) * bias[d_idx8[i][j] * 32 + co];
        bbig[t] = acc;
    }
}

// ---------------- main: implicit-GEMM MFMA, 2-phase double-buffered ----------------
__device__ __forceinline__ void async16(void* lds_dst, const void* g_src) {
    __builtin_amdgcn_global_load_lds(
        (const __attribute__((address_space(1))) unsigned int*)g_src,
        (__attribute__((address_space(3))) unsigned int*)lds_dst,
        16, 0, 0);
}

// One K-step of the pipelined loop.
// CB_CUR/CB_NXT are compile-time-constant LDS byte bases of the two buffers.
// Order per T3-minimum recipe: issue next-tile stage FIRST (overlaps with this
// tile's ds_read+MFMA), then reads+MFMA, then single vmcnt(0)+lgkmcnt(0) drain
// + raw s_barrier.  lgkmcnt(0) before the barrier guarantees every wave's LDS
// reads of CB_CUR completed before anyone overwrites it next step.
#define KSTEP(STEP, CB_CUR, CB_NXT)                                            \
  {                                                                            \
    const int ns = (STEP) + 1;                                                 \
    if (ns < 64) {                                                             \
      const int na  = ns >> 5;                                                 \
      const int ncb = (ns >> 4) & 1;                                           \
      const int go  = ((na ? dh1 : dh0) * HP + (ncb ? dw1 : dw0)) * CIN        \
                      + (ns & 15) * 32;                                        \
      const ushort_t* nap = Abf_t + (size_t)ns * 8192;                         \
      async16(sb + (CB_NXT) + t * 16,         nap);                            \
      async16(sb + (CB_NXT) + 4096 + t * 16,  nap + 2048);                     \
      async16(sb + (CB_NXT) + 8192 + t * 16,  base_r0 + go);                   \
      async16(sb + (CB_NXT) + 12288 + t * 16, base_r1 + go);                   \
    }                                                                          \
    short8 af[4], bf[4];                                                       \
    _Pragma("unroll")                                                          \
    for (int s = 0; s < 4; ++s) {                                              \
      af[s] = *(const short8*)(sb + (CB_CUR) + aoff + s * 1024);               \
      bf[s] = *(const short8*)(sb + (CB_CUR) + boff + s * 1024);               \
    }                                                                          \
    _Pragma("unroll")                                                          \
    for (int sm = 0; sm < 4; ++sm)                                             \
      _Pragma("unroll")                                                        \
      for (int sn = 0; sn < 4; ++sn)                                           \
        acc[sm][sn] = __builtin_amdgcn_mfma_f32_16x16x32_bf16(                 \
            af[sm], bf[sn], acc[sm][sn], 0, 0, 0);                             \
    asm volatile("s_waitcnt vmcnt(0) lgkmcnt(0)" ::: "memory");                \
    __builtin_amdgcn_s_barrier();                                              \
    __builtin_amdgcn_sched_barrier(0);                                         \
  }

__launch_bounds__(256)
__global__ void htconv_mfma(const ushort_t* __restrict__ xpadT,
                            const ushort_t* __restrict__ Abf,
                            const float* __restrict__ bbig,
                            float* __restrict__ out) {
    // Two 16KB buffers; within each: A 128x32 bf16 at [0,8KB), B 128x32 at [8KB,16KB).
    // k-chunk XOR-swizzled by (row>>1)&3 as before (bank-conflict-free, measured 0).
    __shared__ __align__(16) ushort_t smem[16384];
    char* sb = (char*)smem;

    const int t     = threadIdx.x;            // 0..255
    const int ntile = blockIdx.x;             // 0..31 -> ohh0 = 2*ntile
    const int mtile = blockIdx.y;             // 0..1
    const int cls   = blockIdx.z & 3;
    const int b     = blockIdx.z >> 2;
    const int ph = cls >> 1, pw = cls & 1;
    const int ohh0 = ntile * 2;

    // ---- staging addresses ----
    const int srcc = (((t & 3) ^ ((t >> 3) & 3)) * 8);  // swizzled k-chunk (elements)
    const int m_a  = t >> 2;                            // row 0..63 within half-tile
    const ushort_t* Abf_t =
        Abf + (((size_t)cls * 64) * 256 + (size_t)mtile * 128 + m_a) * 32 + srcc;

    const int dh0 = dh_tab[ph][0], dh1 = dh_tab[ph][1];
    const int dw0 = dh_tab[pw][0], dw1 = dh_tab[pw][1];
    const int oww = t >> 2;                             // pixel col 0..63
    const ushort_t* base_r0 =
        xpadT + (((size_t)b * HP + ohh0 + 0 + 1) * HP + oww + 1) * CIN + srcc;
    const ushort_t* base_r1 =
        xpadT + (((size_t)b * HP + ohh0 + 1 + 1) * HP + oww + 1) * CIN + srcc;

    // ---- fragment read offsets (bytes within a buffer) ----
    const int lane = t & 63, wave = t >> 6;
    const int wm = wave >> 1, wn = wave & 1;
    const int col = lane & 15, quad = lane >> 4;
    const int soff = (quad ^ ((col >> 1) & 3)) * 16;    // swizzled 16B chunk
    const int aoff = (wm * 64 + col) * 64 + soff;
    const int boff = 8192 + (wn * 64 + col) * 64 + soff;

    f32x4 acc[4][4];
#pragma unroll
    for (int i = 0; i < 4; ++i)
#pragma unroll
        for (int j = 0; j < 4; ++j)
            acc[i][j] = (f32x4){0.f, 0.f, 0.f, 0.f};

    // ---- prologue: stage step 0 into buffer 0 ----
    {
        const int go0 = (dh0 * HP + dw0) * CIN;         // tap (a=0,c=0), kk=0
        async16(sb + t * 16,         Abf_t);
        async16(sb + 4096 + t * 16,  Abf_t + 2048);
        async16(sb + 8192 + t * 16,  base_r0 + go0);
        async16(sb + 12288 + t * 16, base_r1 + go0);
    }
    asm volatile("s_waitcnt vmcnt(0)" ::: "memory");
    __builtin_amdgcn_s_barrier();
    __builtin_amdgcn_sched_barrier(0);

    // ---- K loop: 64 steps = (a,c) taps x 16 ic-chunks, flattened; 2x unrolled
    //      so buffer parity is compile-time static ----
#pragma unroll 1
    for (int sp = 0; sp < 32; ++sp) {
        KSTEP(2 * sp,     0,     16384);
        KSTEP(2 * sp + 1, 16384, 0);
    }

    // ---- epilogue: bias + stride-2 scatter store ----
    const int oh = 2 * (ohh0 + wn) + ph;
#pragma unroll
    for (int sm = 0; sm < 4; ++sm) {
#pragma unroll
        for (int r = 0; r < 4; ++r) {
            const int occ = mtile * 128 + wm * 64 + sm * 16 + quad * 4 + r;
            const float bv = bbig[occ];
            float* obase = out + (((size_t)b * COUT + occ) * OHW + oh) * OHW + pw;
#pragma unroll
            for (int sn = 0; sn < 4; ++sn) {
                const int owi = sn * 16 + col;          // pixel col 0..63
                obase[2 * owi] = acc[sm][sn][r] + bv;
            }
        }
    }
}

extern "C" void kernel_launch(void* const* d_in, const int* in_sizes, int n_in,
                              void* d_out, int out_size, void* d_ws, size_t ws_size,
                              hipStream_t stream) {
    const float* x    = (const float*)d_in[0];  // [8,512,64,64]
    const float* W    = (const float*)d_in[1];  // [8,64,32,4,4]
    const float* bias = (const float*)d_in[2];  // [8,32]
    float* out = (float*)d_out;                 // [8,256,128,128]

    ushort_t* xpadT = (ushort_t*)d_ws;                       // 8*66*66*512 elems
    ushort_t* Abf   = xpadT + (size_t)NB * HP * HP * CIN;    // 4*64*256*32 elems
    float*    bbig  = (float*)(Abf + (size_t)4 * 64 * 256 * 32);

    // halo-only zeroing: (8*2*66*64 + 8*64*2*64) 16B stores = 133120 threads
    zero_halo<<<dim3(520), 256, 0, stream>>>(xpadT);
    prep_x<<<dim3(H, 32, NB), 256, 0, stream>>>(x, xpadT);
    prep_w<<<dim3((4 * 64 * 256 * 32) / 256), 256, 0, stream>>>(W, bias, Abf, bbig);
    htconv_mfma<<<dim3(32, 2, 32), 256, 0, stream>>>(xpadT, Abf, bbig, out);
}

// Round 2
// 341.346 us; speedup vs baseline: 1.0913x; 1.0464x over previous
//
#include <hip/hip_runtime.h>
#include <hip/hip_bf16.h>

typedef unsigned short ushort_t;
typedef __attribute__((ext_vector_type(8))) short short8;
typedef __attribute__((ext_vector_type(4))) float f32x4;

#define NCOMP    8
#define CIN      512
#define COUT     256
#define H        64
#define HP       66      // padded spatial dim (halo 1 each side)
#define OHW      128
#define NB       8

// Cayley-Dickson |comp| table for n=8 (verified in round 1); sign(i,j)=+1 iff i>=j.
__device__ const int d_idx8[8][8] = {
    {0,1,2,1,4,3,2,3},
    {1,0,3,2,5,4,1,2},
    {2,1,0,1,6,5,4,3},
    {3,2,1,0,7,6,5,4},
    {4,3,2,3,0,1,2,1},
    {5,4,1,2,1,0,3,2},
    {6,5,4,3,2,1,0,1},
    {7,6,5,4,3,2,1,0}};

// Tap tables: output parity p, tap index a: kernel index kh, input offset dh.
__device__ const int kh_tab[2][2] = {{1,3},{0,2}};
__device__ const int dh_tab[2][2] = {{0,-1},{1,0}};

// ---------------- halo zeroing (replaces full-buffer memset) ----------------
__global__ void zero_halo(ushort_t* __restrict__ xpadT) {
    const int t = blockIdx.x * 256 + threadIdx.x;
    const int nA = 8 * 2 * 66 * 64;   // top+bottom full rows, 64 x 16B per cell
    short8 z = {0, 0, 0, 0, 0, 0, 0, 0};
    if (t < nA) {
        int v  = t & 63;
        int r  = t >> 6;              // (b*2 + e)*66 + iw
        int iw = r % 66;
        int q  = r / 66;              // b*2 + e
        int ih = (q & 1) * 65;
        int b  = q >> 1;
        *(short8*)(xpadT + (((size_t)b * HP + ih) * HP + iw) * CIN + v * 8) = z;
    } else {                          // left+right cols, ih 1..64
        int u  = t - nA;
        int v  = u & 63;
        int r  = u >> 6;              // (b*64 + ih-1)*2 + e
        int e  = r & 1;
        int q  = r >> 1;
        int ih = (q & 63) + 1;
        int b  = q >> 6;
        int iw = e * 65;
        *(short8*)(xpadT + (((size_t)b * HP + ih) * HP + iw) * CIN + v * 8) = z;
    }
}

// ---------------- prep: x -> padded, transposed, bf16 ----------------
__global__ void prep_x(const float* __restrict__ x, ushort_t* __restrict__ xpadT) {
    __shared__ ushort_t tile[32][33];
    const int ih  = blockIdx.x;          // 0..63
    const int iw0 = (blockIdx.y & 1) * 32;
    const int ic0 = (blockIdx.y >> 1) * 32;
    const int b   = blockIdx.z;
    const int t   = threadIdx.x;         // 0..255

    for (int e = t; e < 1024; e += 256) {
        int icl = e >> 5, iwl = e & 31;
        float v = x[(((size_t)b * CIN + ic0 + icl) * H + ih) * H + iw0 + iwl];
        __hip_bfloat16 h = __float2bfloat16(v);
        tile[icl][iwl] = *(ushort_t*)&h;
    }
    __syncthreads();
    const int iwl = t >> 3, g = t & 7;   // 32 iw x 8 groups of 4 ic
    ushort4 v;
    v.x = tile[g * 4 + 0][iwl];
    v.y = tile[g * 4 + 1][iwl];
    v.z = tile[g * 4 + 2][iwl];
    v.w = tile[g * 4 + 3][iwl];
    ushort_t* dst = xpadT + (((size_t)b * HP + ih + 1) * HP + iw0 + iwl + 1) * CIN + ic0 + g * 4;
    *(ushort4*)dst = v;
}

// ---------------- prep: fused bf16 weights + bias ----------------
__global__ void prep_w(const float* __restrict__ W, const float* __restrict__ bias,
                       ushort_t* __restrict__ Abf, float* __restrict__ bbig) {
    const int t = blockIdx.x * blockDim.x + threadIdx.x;
    if (t < 4 * 64 * 256 * 32) {
        int kin = t & 31;
        int oc  = (t >> 5) & 255;
        int ks  = (t >> 13) & 63;
        int cls = t >> 19;
        int k  = ks * 32 + kin;
        int a  = k >> 10, c = (k >> 9) & 1, ic = k & 511;
        int ph = cls >> 1, pw = cls & 1;
        int kh = kh_tab[ph][a], kw = kh_tab[pw][c];
        int i = oc >> 5, co = oc & 31;
        int j = ic >> 6, ci = ic & 63;
        float s = (i >= j) ? 1.0f : -1.0f;
        float v = s * W[(((size_t)(d_idx8[i][j] * 64 + ci) * 32 + co) * 4 + kh) * 4 + kw];
        __hip_bfloat16 h = __float2bfloat16(v);
        Abf[t] = *(ushort_t*)&h;
    }
    if (t < COUT) {
        int i = t >> 5, co = t & 31;
        float acc = 0.0f;
        for (int j = 0; j < NCOMP; ++j)
            acc += ((i >= j) ? 1.0f : -1.0f) * bias[d_idx8[i][j] * 32 + co];
        bbig[t] = acc;
    }
}

// ---------------- main: implicit-GEMM MFMA, 3-buffer counted-vmcnt pipeline ----
__device__ __forceinline__ void async16(void* lds_dst, const void* g_src) {
    __builtin_amdgcn_global_load_lds(
        (const __attribute__((address_space(1))) unsigned int*)g_src,
        (__attribute__((address_space(3))) unsigned int*)lds_dst,
        16, 0, 0);
}

// Stage step NS's A+B tiles (4 x 16B per thread) into buffer at byte base CB.
#define STAGE(NS, CB)                                                          \
  {                                                                            \
    const int ns_  = (NS);                                                     \
    const int na_  = ns_ >> 5;                                                 \
    const int ncb_ = (ns_ >> 4) & 1;                                           \
    const int go_  = ((na_ ? dh1 : dh0) * HP + (ncb_ ? dw1 : dw0)) * CIN       \
                     + (ns_ & 15) * 32;                                        \
    const ushort_t* nap_ = Abf_t + (size_t)ns_ * 8192;                         \
    async16(sb + (CB) + t * 16,         nap_);                                 \
    async16(sb + (CB) + 4096 + t * 16,  nap_ + 2048);                          \
    async16(sb + (CB) + 8192 + t * 16,  base_r0 + go_);                        \
    async16(sb + (CB) + 12288 + t * 16, base_r1 + go_);                        \
  }

// ds_read fragments from buffer CB and run the 16-MFMA cluster.
// Plain C++ LDS loads: compiler inserts correct lgkmcnt before MFMA use.
#define COMPUTE(CB)                                                            \
  {                                                                            \
    short8 af[4], bf[4];                                                       \
    _Pragma("unroll")                                                          \
    for (int s = 0; s < 4; ++s) {                                              \
      af[s] = *(const short8*)(sb + (CB) + aoff + s * 1024);                   \
      bf[s] = *(const short8*)(sb + (CB) + boff + s * 1024);                   \
    }                                                                          \
    _Pragma("unroll")                                                          \
    for (int sm = 0; sm < 4; ++sm)                                             \
      _Pragma("unroll")                                                        \
      for (int sn = 0; sn < 4; ++sn)                                           \
        acc[sm][sn] = __builtin_amdgcn_mfma_f32_16x16x32_bf16(                 \
            af[sm], bf[sn], acc[sm][sn], 0, 0, 0);                             \
  }

// Counted wait + barrier.  vmcnt(4): step n's 4 loads retired, step n+1's 4
// stay in flight across the barrier (T4 — never drain to 0 mid-loop).
// Barrier-then-stage makes buffer reuse race-free: every wave past barrier n
// has finished its lgkm-waited reads of step n-1.
#define WAITBAR(N)                                                             \
  asm volatile("s_waitcnt vmcnt(" #N ")" ::: "memory");                        \
  __builtin_amdgcn_s_barrier();                                                \
  __builtin_amdgcn_sched_barrier(0);

__launch_bounds__(256)
__global__ void htconv_mfma(const ushort_t* __restrict__ xpadT,
                            const ushort_t* __restrict__ Abf,
                            const float* __restrict__ bbig,
                            float* __restrict__ out) {
    // Three 16KB buffers (A 8KB | B 8KB each); k-chunk XOR-swizzle unchanged.
    __shared__ __align__(16) ushort_t smem[24576];
    char* sb = (char*)smem;

    const int t     = threadIdx.x;            // 0..255
    const int ntile = blockIdx.x;             // 0..31 -> ohh0 = 2*ntile
    const int mtile = blockIdx.y;             // 0..1
    const int cls   = blockIdx.z & 3;
    const int b     = blockIdx.z >> 2;
    const int ph = cls >> 1, pw = cls & 1;
    const int ohh0 = ntile * 2;

    // ---- staging addresses ----
    const int srcc = (((t & 3) ^ ((t >> 3) & 3)) * 8);  // swizzled k-chunk (elements)
    const int m_a  = t >> 2;                            // row 0..63 within half-tile
    const ushort_t* Abf_t =
        Abf + (((size_t)cls * 64) * 256 + (size_t)mtile * 128 + m_a) * 32 + srcc;

    const int dh0 = dh_tab[ph][0], dh1 = dh_tab[ph][1];
    const int dw0 = dh_tab[pw][0], dw1 = dh_tab[pw][1];
    const int oww = t >> 2;                             // pixel col 0..63
    const ushort_t* base_r0 =
        xpadT + (((size_t)b * HP + ohh0 + 0 + 1) * HP + oww + 1) * CIN + srcc;
    const ushort_t* base_r1 =
        xpadT + (((size_t)b * HP + ohh0 + 1 + 1) * HP + oww + 1) * CIN + srcc;

    // ---- fragment read offsets (bytes within a buffer) ----
    const int lane = t & 63, wave = t >> 6;
    const int wm = wave >> 1, wn = wave & 1;
    const int col = lane & 15, quad = lane >> 4;
    const int soff = (quad ^ ((col >> 1) & 3)) * 16;    // swizzled 16B chunk
    const int aoff = (wm * 64 + col) * 64 + soff;
    const int boff = 8192 + (wn * 64 + col) * 64 + soff;

    f32x4 acc[4][4];
#pragma unroll
    for (int i = 0; i < 4; ++i)
#pragma unroll
        for (int j = 0; j < 4; ++j)
            acc[i][j] = (f32x4){0.f, 0.f, 0.f, 0.f};

    // ---- prologue: stage steps 0,1 into buffers 0,1 (8 loads in flight) ----
    STAGE(0, 0);
    STAGE(1, 16384);

    // ---- 64 K-steps: step n consumes buf n%3; stages step n+2 into (n+2)%3.
    //      Loads for step n issued at step n-2 -> ~2 step-durations of latency
    //      coverage.  Static buffer parity via 3x unroll. ----
#pragma unroll 1
    for (int i = 0; i < 20; ++i) {
        const int n = 3 * i;
        WAITBAR(4); STAGE(n + 2, 32768); COMPUTE(0);
        WAITBAR(4); STAGE(n + 3, 0);     COMPUTE(16384);
        WAITBAR(4); STAGE(n + 4, 16384); COMPUTE(32768);
    }
    // steps 60..63 (stages for 62,63 then drain)
    WAITBAR(4); STAGE(62, 32768); COMPUTE(0);       // step 60
    WAITBAR(4); STAGE(63, 0);     COMPUTE(16384);   // step 61
    WAITBAR(4);                   COMPUTE(32768);   // step 62
    WAITBAR(0);                   COMPUTE(0);       // step 63

    // ---- epilogue: bias + stride-2 scatter store ----
    const int oh = 2 * (ohh0 + wn) + ph;
#pragma unroll
    for (int sm = 0; sm < 4; ++sm) {
#pragma unroll
        for (int r = 0; r < 4; ++r) {
            const int occ = mtile * 128 + wm * 64 + sm * 16 + quad * 4 + r;
            const float bv = bbig[occ];
            float* obase = out + (((size_t)b * COUT + occ) * OHW + oh) * OHW + pw;
#pragma unroll
            for (int sn = 0; sn < 4; ++sn) {
                const int owi = sn * 16 + col;          // pixel col 0..63
                obase[2 * owi] = acc[sm][sn][r] + bv;
            }
        }
    }
}

extern "C" void kernel_launch(void* const* d_in, const int* in_sizes, int n_in,
                              void* d_out, int out_size, void* d_ws, size_t ws_size,
                              hipStream_t stream) {
    const float* x    = (const float*)d_in[0];  // [8,512,64,64]
    const float* W    = (const float*)d_in[1];  // [8,64,32,4,4]
    const float* bias = (const float*)d_in[2];  // [8,32]
    float* out = (float*)d_out;                 // [8,256,128,128]

    ushort_t* xpadT = (ushort_t*)d_ws;                       // 8*66*66*512 elems
    ushort_t* Abf   = xpadT + (size_t)NB * HP * HP * CIN;    // 4*64*256*32 elems
    float*    bbig  = (float*)(Abf + (size_t)4 * 64 * 256 * 32);

    zero_halo<<<dim3(520), 256, 0, stream>>>(xpadT);
    prep_x<<<dim3(H, 32, NB), 256, 0, stream>>>(x, xpadT);
    prep_w<<<dim3((4 * 64 * 256 * 32) / 256), 256, 0, stream>>>(W, bias, Abf, bbig);
    htconv_mfma<<<dim3(32, 2, 32), 256, 0, stream>>>(xpadT, Abf, bbig, out);
}

// Round 3
// 313.031 us; speedup vs baseline: 1.1900x; 1.0905x over previous
//
#include <hip/hip_runtime.h>
#include <hip/hip_bf16.h>

typedef unsigned short ushort_t;
typedef __attribute__((ext_vector_type(8))) short short8;
typedef __attribute__((ext_vector_type(4))) float f32x4;

#define NCOMP    8
#define CIN      512
#define COUT     256
#define H        64
#define HP       66      // padded spatial dim (halo 1 each side)
#define OHW      128
#define NB       8

// Cayley-Dickson |comp| table for n=8; sign(i,j)=+1 iff i>=j.
__device__ const int d_idx8[8][8] = {
    {0,1,2,1,4,3,2,3},
    {1,0,3,2,5,4,1,2},
    {2,1,0,1,6,5,4,3},
    {3,2,1,0,7,6,5,4},
    {4,3,2,3,0,1,2,1},
    {5,4,1,2,1,0,3,2},
    {6,5,4,3,2,1,0,1},
    {7,6,5,4,3,2,1,0}};

// Tap tables: output parity p, tap index a: kernel index kh, input offset dh.
__device__ const int kh_tab[2][2] = {{1,3},{0,2}};
__device__ const int dh_tab[2][2] = {{0,-1},{1,0}};

// ---------------- halo zeroing ----------------
__global__ void zero_halo(ushort_t* __restrict__ xpadT) {
    const int t = blockIdx.x * 256 + threadIdx.x;
    const int nA = 8 * 2 * 66 * 64;   // top+bottom full rows, 64 x 16B per cell
    short8 z = {0, 0, 0, 0, 0, 0, 0, 0};
    if (t < nA) {
        int v  = t & 63;
        int r  = t >> 6;              // (b*2 + e)*66 + iw
        int iw = r % 66;
        int q  = r / 66;              // b*2 + e
        int ih = (q & 1) * 65;
        int b  = q >> 1;
        *(short8*)(xpadT + (((size_t)b * HP + ih) * HP + iw) * CIN + v * 8) = z;
    } else {                          // left+right cols, ih 1..64
        int u  = t - nA;
        int v  = u & 63;
        int r  = u >> 6;              // (b*64 + ih-1)*2 + e
        int e  = r & 1;
        int q  = r >> 1;
        int ih = (q & 63) + 1;
        int b  = q >> 6;
        int iw = e * 65;
        *(short8*)(xpadT + (((size_t)b * HP + ih) * HP + iw) * CIN + v * 8) = z;
    }
}

// ---------------- prep: x -> padded, transposed, bf16 ----------------
__global__ void prep_x(const float* __restrict__ x, ushort_t* __restrict__ xpadT) {
    __shared__ ushort_t tile[32][33];
    const int ih  = blockIdx.x;          // 0..63
    const int iw0 = (blockIdx.y & 1) * 32;
    const int ic0 = (blockIdx.y >> 1) * 32;
    const int b   = blockIdx.z;
    const int t   = threadIdx.x;         // 0..255

    for (int e = t; e < 1024; e += 256) {
        int icl = e >> 5, iwl = e & 31;
        float v = x[(((size_t)b * CIN + ic0 + icl) * H + ih) * H + iw0 + iwl];
        __hip_bfloat16 h = __float2bfloat16(v);
        tile[icl][iwl] = *(ushort_t*)&h;
    }
    __syncthreads();
    const int iwl = t >> 3, g = t & 7;   // 32 iw x 8 groups of 4 ic
    ushort4 v;
    v.x = tile[g * 4 + 0][iwl];
    v.y = tile[g * 4 + 1][iwl];
    v.z = tile[g * 4 + 2][iwl];
    v.w = tile[g * 4 + 3][iwl];
    ushort_t* dst = xpadT + (((size_t)b * HP + ih + 1) * HP + iw0 + iwl + 1) * CIN + ic0 + g * 4;
    *(ushort4*)dst = v;
}

// ---------------- prep: fused bf16 weights + bias ----------------
__global__ void prep_w(const float* __restrict__ W, const float* __restrict__ bias,
                       ushort_t* __restrict__ Abf, float* __restrict__ bbig) {
    const int t = blockIdx.x * blockDim.x + threadIdx.x;
    if (t < 4 * 64 * 256 * 32) {
        int kin = t & 31;
        int oc  = (t >> 5) & 255;
        int ks  = (t >> 13) & 63;
        int cls = t >> 19;
        int k  = ks * 32 + kin;
        int a  = k >> 10, c = (k >> 9) & 1, ic = k & 511;
        int ph = cls >> 1, pw = cls & 1;
        int kh = kh_tab[ph][a], kw = kh_tab[pw][c];
        int i = oc >> 5, co = oc & 31;
        int j = ic >> 6, ci = ic & 63;
        float s = (i >= j) ? 1.0f : -1.0f;
        float v = s * W[(((size_t)(d_idx8[i][j] * 64 + ci) * 32 + co) * 4 + kh) * 4 + kw];
        __hip_bfloat16 h = __float2bfloat16(v);
        Abf[t] = *(ushort_t*)&h;
    }
    if (t < COUT) {
        int i = t >> 5, co = t & 31;
        float acc = 0.0f;
        for (int j = 0; j < NCOMP; ++j)
            acc += ((i >= j) ? 1.0f : -1.0f) * bias[d_idx8[i][j] * 32 + co];
        bbig[t] = acc;
    }
}

// ---------------- main: 256x256-tile implicit-GEMM, 4-buffer counted-vmcnt ----
__device__ __forceinline__ void async16(void* lds_dst, const void* g_src) {
    __builtin_amdgcn_global_load_lds(
        (const __attribute__((address_space(1))) unsigned int*)g_src,
        (__attribute__((address_space(3))) unsigned int*)lds_dst,
        16, 0, 0);
}

// Stage step NS's tiles into 32KB buffer at byte base CB.
// A: 256 oc x 32 kin (16KB) at [CB, CB+16K); B: 256 pixels x 32 kin (16KB) at
// [CB+16K, CB+32K).  4 x async16 per thread (512 threads x 4 x 16B = 32KB).
// LDS dest is t*16-linear per region (global_load_lds requirement); the k-chunk
// swizzle lives in the pre-swizzled global source srcc (both-sides pattern).
#define STAGE(NS, CB)                                                          \
  {                                                                            \
    const int ns_  = (NS);                                                     \
    const int na_  = ns_ >> 5;                                                 \
    const int ncb_ = (ns_ >> 4) & 1;                                           \
    const int go_  = ((na_ ? dh1 : dh0) * HP + (ncb_ ? dw1 : dw0)) * CIN       \
                     + (ns_ & 15) * 32;                                        \
    const ushort_t* nap_ = Abf_t + (size_t)ns_ * 8192;                         \
    async16(sb + (CB) + t * 16,         nap_);                                 \
    async16(sb + (CB) + 8192 + t * 16,  nap_ + 4096);                          \
    async16(sb + (CB) + 16384 + t * 16, base_lo + go_);                        \
    async16(sb + (CB) + 24576 + t * 16, base_hi + go_);                        \
  }

// ds_read fragments from buffer CB and run the 32-MFMA cluster (8 M x 4 N).
#define COMPUTE(CB)                                                            \
  {                                                                            \
    short8 af[8], bf[4];                                                       \
    _Pragma("unroll")                                                          \
    for (int s = 0; s < 8; ++s)                                                \
      af[s] = *(const short8*)(sb + (CB) + aoff + s * 1024);                   \
    _Pragma("unroll")                                                          \
    for (int s = 0; s < 4; ++s)                                                \
      bf[s] = *(const short8*)(sb + (CB) + boff + s * 1024);                   \
    _Pragma("unroll")                                                          \
    for (int sm = 0; sm < 8; ++sm)                                             \
      _Pragma("unroll")                                                        \
      for (int sn = 0; sn < 4; ++sn)                                           \
        acc[sm][sn] = __builtin_amdgcn_mfma_f32_16x16x32_bf16(                 \
            af[sm], bf[sn], acc[sm][sn], 0, 0, 0);                             \
  }

// Counted wait + barrier (T4: never drain to 0 mid-loop).  vmcnt(8): step n's
// 4 loads retired, steps n+1/n+2's 8 stay in flight across the barrier.
// Barrier-then-stage keeps buffer reuse race-free (all waves' lgkm-waited
// reads of the buffer being overwritten completed before the barrier).
#define WAITBAR(N)                                                             \
  asm volatile("s_waitcnt vmcnt(" #N ")" ::: "memory");                        \
  __builtin_amdgcn_s_barrier();                                                \
  __builtin_amdgcn_sched_barrier(0);

__launch_bounds__(512, 2)
__global__ void htconv_mfma(const ushort_t* __restrict__ xpadT,
                            const ushort_t* __restrict__ Abf,
                            const float* __restrict__ bbig,
                            float* __restrict__ out) {
    // Four 32KB buffers (A 16KB | B 16KB each) = 128KB LDS.
    __shared__ __align__(16) ushort_t smem[65536];
    char* sb = (char*)smem;

    const int t     = threadIdx.x;            // 0..511
    const int ntile = blockIdx.x;             // 0..15 -> ohh0 = 4*ntile
    const int cls   = blockIdx.z & 3;
    const int b     = blockIdx.z >> 2;
    const int ph = cls >> 1, pw = cls & 1;
    const int ohh0 = ntile * 4;

    // ---- staging addresses ----
    const int srcc = (((t & 3) ^ ((t >> 3) & 3)) * 8);  // pre-swizzled k-chunk (elems)
    const ushort_t* Abf_t =
        Abf + ((size_t)cls * 64) * 8192 + ((size_t)(t >> 2)) * 32 + srcc;

    const int dh0 = dh_tab[ph][0], dh1 = dh_tab[ph][1];
    const int dw0 = dh_tab[pw][0], dw1 = dh_tab[pw][1];
    const int oww = (t >> 2) & 63;            // pixel col 0..63
    const int rlo = t >> 8;                   // sub-row 0/1 (first B load); +2 for second
    const ushort_t* base_lo =
        xpadT + (((size_t)b * HP + ohh0 + rlo + 1) * HP + oww + 1) * CIN + srcc;
    const ushort_t* base_hi = base_lo + (size_t)2 * HP * CIN;

    // ---- fragment read offsets (bytes within a buffer) ----
    const int lane = t & 63, wave = t >> 6;   // 8 waves: 2 M-warps x 4 N-warps
    const int wm = wave >> 2, wn = wave & 3;
    const int col = lane & 15, quad = lane >> 4;
    const int soff = (quad ^ ((col >> 1) & 3)) * 16;    // swizzled 16B chunk
    const int aoff = (wm * 128 + col) * 64 + soff;            // A rows [wm*128, +128)
    const int boff = 16384 + (wn * 64 + col) * 64 + soff;     // B pixels [wn*64, +64)

    f32x4 acc[8][4];
#pragma unroll
    for (int i = 0; i < 8; ++i)
#pragma unroll
        for (int j = 0; j < 4; ++j)
            acc[i][j] = (f32x4){0.f, 0.f, 0.f, 0.f};

    // ---- prologue: stage steps 0,1,2 into buffers 0,1,2 (12 loads in flight) ----
    STAGE(0, 0);
    STAGE(1, 32768);
    STAGE(2, 65536);

    // ---- 64 K-steps: step s consumes buf s%4, stages s+3 into (s+3)%4.
    //      Issue-to-consume distance = 3 steps of latency coverage. ----
#pragma unroll 1
    for (int i = 0; i < 15; ++i) {
        const int n = 4 * i;
        WAITBAR(8); STAGE(n + 3, 98304); COMPUTE(0);
        WAITBAR(8); STAGE(n + 4, 0);     COMPUTE(32768);
        WAITBAR(8); STAGE(n + 5, 32768); COMPUTE(65536);
        WAITBAR(8); STAGE(n + 6, 65536); COMPUTE(98304);
    }
    // steps 60..63
    WAITBAR(8); STAGE(63, 98304); COMPUTE(0);       // step 60
    WAITBAR(8);                   COMPUTE(32768);   // step 61
    WAITBAR(4);                   COMPUTE(65536);   // step 62
    WAITBAR(0);                   COMPUTE(98304);   // step 63

    // ---- epilogue: bias + stride-2 scatter store ----
    const int oh = 2 * (ohh0 + wn) + ph;
#pragma unroll
    for (int sm = 0; sm < 8; ++sm) {
#pragma unroll
        for (int r = 0; r < 4; ++r) {
            const int occ = wm * 128 + sm * 16 + quad * 4 + r;
            const float bv = bbig[occ];
            float* obase = out + (((size_t)b * COUT + occ) * OHW + oh) * OHW + pw;
#pragma unroll
            for (int sn = 0; sn < 4; ++sn) {
                const int owi = sn * 16 + col;          // pixel col 0..63
                obase[2 * owi] = acc[sm][sn][r] + bv;
            }
        }
    }
}

extern "C" void kernel_launch(void* const* d_in, const int* in_sizes, int n_in,
                              void* d_out, int out_size, void* d_ws, size_t ws_size,
                              hipStream_t stream) {
    const float* x    = (const float*)d_in[0];  // [8,512,64,64]
    const float* W    = (const float*)d_in[1];  // [8,64,32,4,4]
    const float* bias = (const float*)d_in[2];  // [8,32]
    float* out = (float*)d_out;                 // [8,256,128,128]

    ushort_t* xpadT = (ushort_t*)d_ws;                       // 8*66*66*512 elems
    ushort_t* Abf   = xpadT + (size_t)NB * HP * HP * CIN;    // 4*64*256*32 elems
    float*    bbig  = (float*)(Abf + (size_t)4 * 64 * 256 * 32);

    zero_halo<<<dim3(520), 256, 0, stream>>>(xpadT);
    prep_x<<<dim3(H, 32, NB), 256, 0, stream>>>(x, xpadT);
    prep_w<<<dim3((4 * 64 * 256 * 32) / 256), 256, 0, stream>>>(W, bias, Abf, bbig);
    htconv_mfma<<<dim3(16, 1, 32), 512, 0, stream>>>(xpadT, Abf, bbig, out);
}

// Round 4
// 307.916 us; speedup vs baseline: 1.2097x; 1.0166x over previous
//
#include <hip/hip_runtime.h>
#include <hip/hip_bf16.h>

typedef unsigned short ushort_t;
typedef __attribute__((ext_vector_type(8))) short short8;
typedef __attribute__((ext_vector_type(4))) float f32x4;

#define NCOMP    8
#define CIN      512
#define COUT     256
#define H        64
#define HP       66      // padded spatial dim (halo 1 each side)
#define OHW      128
#define NB       8

// Cayley-Dickson |comp| table for n=8; sign(i,j)=+1 iff i>=j.
__device__ const int d_idx8[8][8] = {
    {0,1,2,1,4,3,2,3},
    {1,0,3,2,5,4,1,2},
    {2,1,0,1,6,5,4,3},
    {3,2,1,0,7,6,5,4},
    {4,3,2,3,0,1,2,1},
    {5,4,1,2,1,0,3,2},
    {6,5,4,3,2,1,0,1},
    {7,6,5,4,3,2,1,0}};

// Tap tables: output parity p, tap index a: kernel index kh, input offset dh.
__device__ const int kh_tab[2][2] = {{1,3},{0,2}};
__device__ const int dh_tab[2][2] = {{0,-1},{1,0}};

// ---------------- prep: x -> padded, transposed, bf16 (fused halo) ----------
// One block per (b, ih) row: coalesced float4 reads of x[b,:,ih,:] (128KB),
// LDS transpose (write swizzle ic^(iv<<3): 2-way write conflicts = free,
// b128 reads conflict-free via XOR lane permutation), ushort8 contiguous
// 64KB row write + this row's two halo cells.  blockIdx.x==64: pad rows.
__global__ void prep_x2(const float* __restrict__ x, ushort_t* __restrict__ xpadT) {
    __shared__ __align__(16) ushort_t lds[64 * 512];
    const int t = threadIdx.x;        // 0..255
    const int b = blockIdx.y;
    const int ihb = blockIdx.x;       // 0..64; 64 => both pad rows

    if (ihb == 64) {                  // ih_pad = 0 and 65: full zero rows
        short8 z = {0,0,0,0,0,0,0,0};
        ushort_t* r0 = xpadT + ((size_t)b * HP + 0)  * HP * CIN;
        ushort_t* r1 = xpadT + ((size_t)b * HP + 65) * HP * CIN;
        for (int e = t; e < (HP * CIN) / 8; e += 256) {   // 4224 ushort8
            *(short8*)(r0 + e * 8) = z;
            *(short8*)(r1 + e * 8) = z;
        }
        return;
    }
    const int ih = ihb;

    // ---- phase 1: load + convert + transposed swizzled LDS store ----
    const int iv      = t & 15;       // float4 index within row (iw = 4*iv+j)
    const int ic_base = t >> 4;       // 0..15
    const float* xr = x + ((size_t)b * CIN * H + ih) * H;
#pragma unroll 8
    for (int r = 0; r < 32; ++r) {
        const int ic = r * 16 + ic_base;
        const float4 v = *(const float4*)(xr + (size_t)ic * H * H + iv * 4);
        const int swz_ic = ic ^ (iv << 3);        // g(iw) = (iw>>2)<<3 = iv*8
        __hip_bfloat16 h0 = __float2bfloat16(v.x);
        __hip_bfloat16 h1 = __float2bfloat16(v.y);
        __hip_bfloat16 h2 = __float2bfloat16(v.z);
        __hip_bfloat16 h3 = __float2bfloat16(v.w);
        lds[(iv * 4 + 0) * 512 + swz_ic] = *(ushort_t*)&h0;
        lds[(iv * 4 + 1) * 512 + swz_ic] = *(ushort_t*)&h1;
        lds[(iv * 4 + 2) * 512 + swz_ic] = *(ushort_t*)&h2;
        lds[(iv * 4 + 3) * 512 + swz_ic] = *(ushort_t*)&h3;
    }
    __syncthreads();

    // ---- phase 2: contiguous 64KB interior write + 2 halo cells ----
    ushort_t* rowc = xpadT + (((size_t)b * HP + ih + 1) * HP) * CIN; // iw_pad=0
    ushort_t* dst  = rowc + CIN;                                     // iw_pad=1
#pragma unroll
    for (int r = 0; r < 16; ++r) {
        const int e   = r * 256 + t;
        const int iw  = e >> 6;                   // constant per wave
        const int ic0 = (e & 63) * 8;
        const int off = iw * 512 + (ic0 ^ ((iw >> 2) << 3));
        *(short8*)(dst + (size_t)e * 8) = *(const short8*)(lds + off);
    }
    if (t < 128) {                                // halo cells iw_pad 0 and 65
        short8 z = {0,0,0,0,0,0,0,0};
        const int l = t & 63;
        ushort_t* hc = (t < 64) ? rowc : (rowc + 65 * CIN);
        *(short8*)(hc + l * 8) = z;
    }
}

// ---------------- prep: fused bf16 weights + bias ----------------
__global__ void prep_w(const float* __restrict__ W, const float* __restrict__ bias,
                       ushort_t* __restrict__ Abf, float* __restrict__ bbig) {
    const int t = blockIdx.x * blockDim.x + threadIdx.x;
    if (t < 4 * 64 * 256 * 32) {
        int kin = t & 31;
        int oc  = (t >> 5) & 255;
        int ks  = (t >> 13) & 63;
        int cls = t >> 19;
        int k  = ks * 32 + kin;
        int a  = k >> 10, c = (k >> 9) & 1, ic = k & 511;
        int ph = cls >> 1, pw = cls & 1;
        int kh = kh_tab[ph][a], kw = kh_tab[pw][c];
        int i = oc >> 5, co = oc & 31;
        int j = ic >> 6, ci = ic & 63;
        float s = (i >= j) ? 1.0f : -1.0f;
        float v = s * W[(((size_t)(d_idx8[i][j] * 64 + ci) * 32 + co) * 4 + kh) * 4 + kw];
        __hip_bfloat16 h = __float2bfloat16(v);
        Abf[t] = *(ushort_t*)&h;
    }
    if (t < COUT) {
        int i = t >> 5, co = t & 31;
        float acc = 0.0f;
        for (int j = 0; j < NCOMP; ++j)
            acc += ((i >= j) ? 1.0f : -1.0f) * bias[d_idx8[i][j] * 32 + co];
        bbig[t] = acc;
    }
}

// ---------------- main: 256x256-tile implicit-GEMM, 4-buffer counted-vmcnt ----
__device__ __forceinline__ void async16(void* lds_dst, const void* g_src) {
    __builtin_amdgcn_global_load_lds(
        (const __attribute__((address_space(1))) unsigned int*)g_src,
        (__attribute__((address_space(3))) unsigned int*)lds_dst,
        16, 0, 0);
}

// Stage step NS's tiles into 32KB buffer at byte base CB.
#define STAGE(NS, CB)                                                          \
  {                                                                            \
    const int ns_  = (NS);                                                     \
    const int na_  = ns_ >> 5;                                                 \
    const int ncb_ = (ns_ >> 4) & 1;                                           \
    const int go_  = ((na_ ? dh1 : dh0) * HP + (ncb_ ? dw1 : dw0)) * CIN       \
                     + (ns_ & 15) * 32;                                        \
    const ushort_t* nap_ = Abf_t + (size_t)ns_ * 8192;                         \
    async16(sb + (CB) + t * 16,         nap_);                                 \
    async16(sb + (CB) + 8192 + t * 16,  nap_ + 4096);                          \
    async16(sb + (CB) + 16384 + t * 16, base_lo + go_);                        \
    async16(sb + (CB) + 24576 + t * 16, base_hi + go_);                        \
  }

// ds_read fragments from buffer CB and run the 32-MFMA cluster (8 M x 4 N),
// T5: setprio(1) around the MFMA cluster (counted-vmcnt phase-split structure
// has wave role diversity -> scheduler favors MFMA-entering waves).
#define COMPUTE(CB)                                                            \
  {                                                                            \
    short8 af[8], bf[4];                                                       \
    _Pragma("unroll")                                                          \
    for (int s = 0; s < 8; ++s)                                                \
      af[s] = *(const short8*)(sb + (CB) + aoff + s * 1024);                   \
    _Pragma("unroll")                                                          \
    for (int s = 0; s < 4; ++s)                                                \
      bf[s] = *(const short8*)(sb + (CB) + boff + s * 1024);                   \
    __builtin_amdgcn_s_setprio(1);                                             \
    _Pragma("unroll")                                                          \
    for (int sm = 0; sm < 8; ++sm)                                             \
      _Pragma("unroll")                                                        \
      for (int sn = 0; sn < 4; ++sn)                                           \
        acc[sm][sn] = __builtin_amdgcn_mfma_f32_16x16x32_bf16(                 \
            af[sm], bf[sn], acc[sm][sn], 0, 0, 0);                             \
    __builtin_amdgcn_s_setprio(0);                                             \
  }

// Counted wait + barrier (T4: never drain to 0 mid-loop).
#define WAITBAR(N)                                                             \
  asm volatile("s_waitcnt vmcnt(" #N ")" ::: "memory");                        \
  __builtin_amdgcn_s_barrier();                                                \
  __builtin_amdgcn_sched_barrier(0);

__launch_bounds__(512, 2)
__global__ void htconv_mfma(const ushort_t* __restrict__ xpadT,
                            const ushort_t* __restrict__ Abf,
                            const float* __restrict__ bbig,
                            float* __restrict__ out) {
    // Four 32KB buffers (A 16KB | B 16KB each) = 128KB LDS.
    __shared__ __align__(16) ushort_t smem[65536];
    char* sb = (char*)smem;

    const int t     = threadIdx.x;            // 0..511
    const int ntile = blockIdx.x;             // 0..15 -> ohh0 = 4*ntile
    const int cls   = blockIdx.z & 3;
    const int b     = blockIdx.z >> 2;
    const int ph = cls >> 1, pw = cls & 1;
    const int ohh0 = ntile * 4;

    // ---- staging addresses ----
    const int srcc = (((t & 3) ^ ((t >> 3) & 3)) * 8);  // pre-swizzled k-chunk (elems)
    const ushort_t* Abf_t =
        Abf + ((size_t)cls * 64) * 8192 + ((size_t)(t >> 2)) * 32 + srcc;

    const int dh0 = dh_tab[ph][0], dh1 = dh_tab[ph][1];
    const int dw0 = dh_tab[pw][0], dw1 = dh_tab[pw][1];
    const int oww = (t >> 2) & 63;            // pixel col 0..63
    const int rlo = t >> 8;                   // sub-row 0/1 (first B load); +2 for second
    const ushort_t* base_lo =
        xpadT + (((size_t)b * HP + ohh0 + rlo + 1) * HP + oww + 1) * CIN + srcc;
    const ushort_t* base_hi = base_lo + (size_t)2 * HP * CIN;

    // ---- fragment read offsets (bytes within a buffer) ----
    const int lane = t & 63, wave = t >> 6;   // 8 waves: 2 M-warps x 4 N-warps
    const int wm = wave >> 2, wn = wave & 3;
    const int col = lane & 15, quad = lane >> 4;
    const int soff = (quad ^ ((col >> 1) & 3)) * 16;    // swizzled 16B chunk
    const int aoff = (wm * 128 + col) * 64 + soff;            // A rows [wm*128, +128)
    const int boff = 16384 + (wn * 64 + col) * 64 + soff;     // B pixels [wn*64, +64)

    f32x4 acc[8][4];
#pragma unroll
    for (int i = 0; i < 8; ++i)
#pragma unroll
        for (int j = 0; j < 4; ++j)
            acc[i][j] = (f32x4){0.f, 0.f, 0.f, 0.f};

    // ---- prologue: stage steps 0,1,2 into buffers 0,1,2 (12 loads in flight) ----
    STAGE(0, 0);
    STAGE(1, 32768);
    STAGE(2, 65536);

    // ---- 64 K-steps: step s consumes buf s%4, stages s+3 into (s+3)%4. ----
#pragma unroll 1
    for (int i = 0; i < 15; ++i) {
        const int n = 4 * i;
        WAITBAR(8); STAGE(n + 3, 98304); COMPUTE(0);
        WAITBAR(8); STAGE(n + 4, 0);     COMPUTE(32768);
        WAITBAR(8); STAGE(n + 5, 32768); COMPUTE(65536);
        WAITBAR(8); STAGE(n + 6, 65536); COMPUTE(98304);
    }
    // steps 60..63
    WAITBAR(8); STAGE(63, 98304); COMPUTE(0);       // step 60
    WAITBAR(8);                   COMPUTE(32768);   // step 61
    WAITBAR(4);                   COMPUTE(65536);   // step 62
    WAITBAR(0);                   COMPUTE(98304);   // step 63

    // ---- epilogue: bias + stride-2 scatter store ----
    const int oh = 2 * (ohh0 + wn) + ph;
#pragma unroll
    for (int sm = 0; sm < 8; ++sm) {
#pragma unroll
        for (int r = 0; r < 4; ++r) {
            const int occ = wm * 128 + sm * 16 + quad * 4 + r;
            const float bv = bbig[occ];
            float* obase = out + (((size_t)b * COUT + occ) * OHW + oh) * OHW + pw;
#pragma unroll
            for (int sn = 0; sn < 4; ++sn) {
                const int owi = sn * 16 + col;          // pixel col 0..63
                obase[2 * owi] = acc[sm][sn][r] + bv;
            }
        }
    }
}

extern "C" void kernel_launch(void* const* d_in, const int* in_sizes, int n_in,
                              void* d_out, int out_size, void* d_ws, size_t ws_size,
                              hipStream_t stream) {
    const float* x    = (const float*)d_in[0];  // [8,512,64,64]
    const float* W    = (const float*)d_in[1];  // [8,64,32,4,4]
    const float* bias = (const float*)d_in[2];  // [8,32]
    float* out = (float*)d_out;                 // [8,256,128,128]

    ushort_t* xpadT = (ushort_t*)d_ws;                       // 8*66*66*512 elems
    ushort_t* Abf   = xpadT + (size_t)NB * HP * HP * CIN;    // 4*64*256*32 elems
    float*    bbig  = (float*)(Abf + (size_t)4 * 64 * 256 * 32);

    prep_x2<<<dim3(65, NB), 256, 0, stream>>>(x, xpadT);
    prep_w<<<dim3((4 * 64 * 256 * 32) / 256), 256, 0, stream>>>(W, bias, Abf, bbig);
    htconv_mfma<<<dim3(16, 1, 32), 512, 0, stream>>>(xpadT, Abf, bbig, out);
}